// Round 3
// baseline (101.167 us; speedup 1.0000x reference)
//
#include <hip/hip_runtime.h>
#include <cstdint>
#include <cstddef>

#define NPTS   4096
#define BATCH  4
#define KNN    8
#define NC     16          // chunks per cloud scan
#define CHN    (NPTS / NC) // 256 candidates per chunk
#define PD     4           // partial STORAGE depth per chunk (uint4; slot 3 = pad)
#define SD     3           // scan list depth (top-3/chunk)
#define EPS_F  1e-12f
#define NBLK2  ((BATCH * NPTS) / 64)   // 256 loss blocks

typedef __attribute__((ext_vector_type(16))) float sf16;  // 16 SGPRs

__device__ __forceinline__ uint32_t u32min(uint32_t a, uint32_t b) { return a < b ? a : b; }
__device__ __forceinline__ uint32_t u32max(uint32_t a, uint32_t b) { return a > b ? a : b; }

// v_med3_u32: for sorted a<=b, med3(a,b,x) == clamp(x,a,b) — one instruction.
__device__ __forceinline__ uint32_t umed3(uint32_t a, uint32_t b, uint32_t c) {
  uint32_t d;
  asm("v_med3_u32 %0, %1, %2, %3" : "=v"(d) : "v"(a), "v"(b), "v"(c));
  return d;
}

// Insert key into ascending D-list, dropping the largest: 1 min + (D-1) med3.
template <int D>
__device__ __forceinline__ void insertD(uint32_t (&loc)[D], uint32_t key) {
  uint32_t prev = loc[0];
  loc[0] = u32min(prev, key);
#pragma unroll
  for (int m = 1; m < D; ++m) {
    const uint32_t cur = loc[m];
    loc[m] = umed3(prev, cur, key);
    prev = cur;
  }
}

// Packed sidecar layout: 8 points x [x,y,z,|q|^2] = 32 floats per sub-chunk.
// CP(c,f): float f of candidate c, from two sf16 SGPR buffers.
#define CP(c, f) (((c) < 4) ? A[4 * (c) + (f)] : B[4 * ((c) - 4) + (f)])

// 8 candidates, norm-form distance: d2 = np + nq - 2*dot. 5 VALU ops
// (3 fma-chain with one SGPR coord each, fmaf(-2,dot,np), +s_nq), then
// fused and_or key (1) + insert (3) = 9 ops/candidate (was 10).
// Self-pair: dot is computed with the IDENTICAL fma tree as np/nq, so
// t == np bitwise, fmaf(-2,t,np) == -np exactly, d2 == nq - np == 0.0
// exactly -> self still ranks 0 and the rank-0 drop stays sound.
template <int D>
__device__ __forceinline__ void body8(const sf16& A, const sf16& B, int jb,
                                      float xix, float xiy, float xiz, float np,
                                      uint32_t (&loc)[D]) {
#pragma unroll
  for (int c = 0; c < 8; ++c) {
    float t = fmaf(CP(c, 0), xix, fmaf(CP(c, 1), xiy, CP(c, 2) * xiz));
    t = fmaf(-2.0f, t, np);
    const float d2 = CP(c, 3) + t;
    const uint32_t key = (__float_as_uint(d2) & 0xFFFFF000u) | (uint32_t)(jb + c);
    insertD<D>(loc, key);
  }
}

// Scan one 256-point chunk streamed through SGPRs from the packed sidecar.
// Double-buffered 8-point sub-chunks (32 floats = 2 x s_load_dwordx16).
// SMEM completes out of order -> lgkmcnt(0) full drain; sched_barrier(0)
// after each wait pins the dependent VALU below it (rule #18).
template <int D>
__device__ __forceinline__ void scan_chunk_s(const float* __restrict__ sp, int j0,
                                             float xix, float xiy, float xiz, float np,
                                             uint32_t (&loc)[D]) {
#pragma unroll
  for (int k = 0; k < D; ++k) loc[k] = 0xFFFFFFFFu;

  sf16 a0, b0, a1, b1;
  asm volatile("s_load_dwordx16 %0, %2, 0x0\n\t"
               "s_load_dwordx16 %1, %2, 0x40"
               : "=&s"(a0), "=&s"(b0) : "s"(sp));
  asm volatile("s_waitcnt lgkmcnt(0)" ::: "memory");
  __builtin_amdgcn_sched_barrier(0);

#pragma unroll 1
  for (int s = 0; s < 32; s += 2) {
    {  // issue sub s+1 into buf1; compute sub s from buf0
      const float* nx = sp + 32 * (s + 1);
      asm volatile("s_load_dwordx16 %0, %2, 0x0\n\t"
                   "s_load_dwordx16 %1, %2, 0x40"
                   : "=&s"(a1), "=&s"(b1) : "s"(nx));
      body8<D>(a0, b0, j0 + 8 * s, xix, xiy, xiz, np, loc);
      asm volatile("s_waitcnt lgkmcnt(0)" ::: "memory");
      __builtin_amdgcn_sched_barrier(0);
    }
    {  // issue sub s+2 (clamped; last iter re-loads 31 harmlessly) into buf0;
       // compute sub s+1 from buf1
      const int s2 = (s + 2 < 32) ? (s + 2) : 31;
      const float* nx = sp + 32 * s2;
      asm volatile("s_load_dwordx16 %0, %2, 0x0\n\t"
                   "s_load_dwordx16 %1, %2, 0x40"
                   : "=&s"(a0), "=&s"(b0) : "s"(nx));
      body8<D>(a1, b1, j0 + 8 * (s + 1), xix, xiy, xiz, np, loc);
      asm volatile("s_waitcnt lgkmcnt(0)" ::: "memory");
      __builtin_amdgcn_sched_barrier(0);
    }
  }
}

// ---------------------------------------------------------------------------
// Kernel 1: per-(cloud,batch,point,chunk) top-3 by truncated key (top-4 with
// rank-0 self-drop for the self chunk — block-uniform branch). Key =
// (float_bits(d2) & 0xFFFFF000) | j; ties -> ascending j (lax.top_k).
// Change vs R2: norm-form distance (9 ops/cand vs 10). Each block packs its
// chunk's [x,y,z,|q|^2] into a private sidecar (vector stores -> syncthreads
// -> s_load; K$ invalidated at dispatch so no stale lines), then SGPR-streams
// it. d2 rounding differs from the exact-diff form by ~4e-7 abs vs key
// granularity ~8e-6 — rare ±1-bucket flips, below the accepted SD=3 noise.
// ---------------------------------------------------------------------------
__global__ void __launch_bounds__(256, 8)
knn_partial_k(const float* __restrict__ pred, const float* __restrict__ tgt,
              uint32_t* __restrict__ partial, float* __restrict__ pside,
              uint32_t* __restrict__ ticket) {
  if (blockIdx.x == 0 && threadIdx.x == 0) *ticket = 0u;

  int bx = blockIdx.x;
  const int chunk = bx & (NC - 1); bx /= NC;
  const int ig    = bx & 15; bx >>= 4;
  const int b     = bx & 3;  bx >>= 2;
  const int cloud = bx;  // 0 = pred, 1 = target

  const float* __restrict__ pts = (cloud ? tgt : pred) + (size_t)b * NPTS * 3;
  const int tid = threadIdx.x;
  const int i = ig * 256 + tid;
  const int j0 = chunk * CHN;

  const float xix = pts[3 * i + 0];
  const float xiy = pts[3 * i + 1];
  const float xiz = pts[3 * i + 2];
  const float np  = fmaf(xix, xix, fmaf(xiy, xiy, xiz * xiz));

  // Pack this block's chunk into the private sidecar: one point per thread.
  float* __restrict__ myp = pside + (size_t)blockIdx.x * CHN * 4;
  {
    const int j = j0 + tid;
    const float cx = pts[3 * j + 0];
    const float cy = pts[3 * j + 1];
    const float cz = pts[3 * j + 2];
    const float nq = fmaf(cx, cx, fmaf(cy, cy, cz * cz));
    *(float4*)(myp + 4 * tid) = make_float4(cx, cy, cz, nq);
  }
  __syncthreads();   // vmcnt(0)+barrier: stores in L2 (write-through L1)

  uint4 o;
  if (ig == chunk) {           // self chunk (CHN == 256): depth 4, drop rank 0
    uint32_t loc[SD + 1];
    scan_chunk_s<SD + 1>(myp, j0, xix, xiy, xiz, np, loc);
    o = make_uint4(loc[1], loc[2], loc[3], 0xFFFFFFFFu);
  } else {
    uint32_t loc[SD];
    scan_chunk_s<SD>(myp, j0, xix, xiy, xiz, np, loc);
    o = make_uint4(loc[0], loc[1], loc[2], 0xFFFFFFFFu);
  }
  uint32_t* p = partial +
      ((((size_t)(cloud * BATCH + b) * NC + chunk) * NPTS) + (size_t)i) * PD;
  *(uint4*)p = o;
}

// Merge two sorted-ascending 8-lists, keep the smallest 8, sorted.
__device__ __forceinline__ void merge2(uint32_t A[KNN], const uint32_t B[KNN]) {
  uint32_t t[KNN];
#pragma unroll
  for (int m = 0; m < KNN; ++m) t[m] = u32min(A[m], B[KNN - 1 - m]);
#define CEU(x, y) { uint32_t lo = u32min(t[x], t[y]); uint32_t hi = u32max(t[x], t[y]); t[x] = lo; t[y] = hi; }
  CEU(0,4) CEU(1,5) CEU(2,6) CEU(3,7)
  CEU(0,2) CEU(1,3) CEU(4,6) CEU(5,7)
  CEU(0,1) CEU(2,3) CEU(4,5) CEU(6,7)
#undef CEU
#pragma unroll
  for (int m = 0; m < KNN; ++m) A[m] = t[m];
}

// Two sorted-4 lists -> one fully sorted 8 (bitonic cleanup, 12 CEs).
// Pad entries (0xFFFFFFFF) sort to the top and never reach the final top-8
// (16 chunks x 3 real keys = 48 >= 8 real candidates).
__device__ __forceinline__ void merge44(const uint2 a0, const uint2 a1,
                                        const uint2 b0, const uint2 b1,
                                        uint32_t s[KNN]) {
  s[0] = a0.x; s[1] = a0.y; s[2] = a1.x; s[3] = a1.y;
  s[4] = b1.y; s[5] = b1.x; s[6] = b0.y; s[7] = b0.x;  // b reversed -> bitonic
#define CEU(x, y) { uint32_t lo = u32min(s[x], s[y]); uint32_t hi = u32max(s[x], s[y]); s[x] = lo; s[y] = hi; }
  CEU(0,4) CEU(1,5) CEU(2,6) CEU(3,7)
  CEU(0,2) CEU(1,3) CEU(4,6) CEU(5,7)
  CEU(0,1) CEU(2,3) CEU(4,5) CEU(6,7)
#undef CEU
}

// Merge all NC=16 sorted-4 lists for point i -> global top-8 (sorted).
__device__ __forceinline__ void merge_all(const uint32_t* __restrict__ base,
                                          int i, uint32_t v[KNN]) {
  const size_t stride = (size_t)NPTS * PD;
  const uint32_t* p = base + (size_t)i * PD;
  uint2 q[NC][2];
#pragma unroll
  for (int c = 0; c < NC; ++c) {
    q[c][0] = *(const uint2*)(p + (size_t)c * stride);
    q[c][1] = *(const uint2*)(p + (size_t)c * stride + 2);
  }
  uint32_t L[NC / 2][KNN];
#pragma unroll
  for (int c = 0; c < NC / 2; ++c)
    merge44(q[2 * c][0], q[2 * c][1], q[2 * c + 1][0], q[2 * c + 1][1], L[c]);
  merge2(L[0], L[1]); merge2(L[2], L[3]); merge2(L[4], L[5]); merge2(L[6], L[7]);
  merge2(L[0], L[2]); merge2(L[4], L[6]);
  merge2(L[0], L[4]);
#pragma unroll
  for (int m = 0; m < KNN; ++m) v[m] = L[0][m];
}

// Per-cloud: coord gather (8 independent loads), density/cov/unit vectors.
__device__ __forceinline__ void cloud_stats(const float* __restrict__ C, int i,
                                            const uint32_t v[KNN],
                                            float& dsum, float cov[6],
                                            float nx[KNN], float ny[KNN], float nz[KNN]) {
  const float qx = C[3 * i], qy = C[3 * i + 1], qz = C[3 * i + 2];
  float jx[KNN], jy[KNN], jz[KNN];
#pragma unroll
  for (int k = 0; k < KNN; ++k) {
    const int j = (int)(v[k] & 0xFFFu);
    jx[k] = C[3 * j]; jy[k] = C[3 * j + 1]; jz[k] = C[3 * j + 2];
  }
  dsum = 0.f;
#pragma unroll
  for (int m = 0; m < 6; ++m) cov[m] = 0.f;
#pragma unroll
  for (int k = 0; k < KNN; ++k) {
    const float ax = jx[k] - qx, ay = jy[k] - qy, az = jz[k] - qz;
    const float d2 = fmaf(ax, ax, fmaf(ay, ay, az * az));
    const float dist = sqrtf(fmaxf(d2, EPS_F));
    const float inv = 1.0f / fmaxf(dist, EPS_F);
    dsum += dist;
    cov[0] += ax * ax; cov[1] += ay * ay; cov[2] += az * az;
    cov[3] += ax * ay; cov[4] += ax * az; cov[5] += ay * az;
    nx[k] = ax * inv; ny[k] = ay * inv; nz[k] = az * inv;
  }
}

// ---------------------------------------------------------------------------
// Kernel 2 — R1/R2 verbatim (proven): plain per-block stores + ticket finalize.
// ---------------------------------------------------------------------------
__global__ void __launch_bounds__(64, 1)
loss_k(const float* __restrict__ pred, const float* __restrict__ tgt,
       const uint32_t* __restrict__ partial, double* __restrict__ bsum,
       uint32_t* __restrict__ ticket, float* __restrict__ out) {
  const int p = blockIdx.x * 64 + threadIdx.x;   // 0 .. 16383
  const int b = p >> 12;
  const int i = p & (NPTS - 1);

  const float* __restrict__ P = pred + (size_t)b * NPTS * 3;
  const float* __restrict__ T = tgt  + (size_t)b * NPTS * 3;

  const size_t cstride = (size_t)NC * NPTS * PD;
  uint32_t vp[KNN], vt[KNN];
  merge_all(partial + (size_t)(0 * BATCH + b) * cstride, i, vp);
  merge_all(partial + (size_t)(1 * BATCH + b) * cstride, i, vt);

  float dsp, dst, pcov[6], tcov[6];
  float pnx[KNN], pny[KNN], pnz[KNN], tnx[KNN], tny[KNN], tnz[KNN];
  cloud_stats(P, i, vp, dsp, pcov, pnx, pny, pnz);
  cloud_stats(T, i, vt, dst, tcov, tnx, tny, tnz);

  float sdot = 0.f;
#pragma unroll
  for (int k = 0; k < KNN; ++k)
    sdot += pnx[k] * tnx[k] + pny[k] * tny[k] + pnz[k] * tnz[k];

  const float densp = dsp * (1.0f / KNN);
  const float denst = dst * (1.0f / KNN);
  float e = (densp - denst) * (densp - denst);

  const float dxx = (pcov[0] - tcov[0]) * (1.0f / KNN);
  const float dyy = (pcov[1] - tcov[1]) * (1.0f / KNN);
  const float dzz = (pcov[2] - tcov[2]) * (1.0f / KNN);
  const float dxy = (pcov[3] - tcov[3]) * (1.0f / KNN);
  const float dxz = (pcov[4] - tcov[4]) * (1.0f / KNN);
  const float dyz = (pcov[5] - tcov[5]) * (1.0f / KNN);
  float cfro = sqrtf(dxx * dxx + dyy * dyy + dzz * dzz
                     + 2.0f * (dxy * dxy + dxz * dxz + dyz * dyz));
  float s = sdot;

#pragma unroll
  for (int off = 32; off > 0; off >>= 1) {
    e    += __shfl_down(e, off);
    s    += __shfl_down(s, off);
    cfro += __shfl_down(cfro, off);
  }

  unsigned rank = 0u;
  if (threadIdx.x == 0) {
    double* d = bsum + 3 * (size_t)blockIdx.x;
    d[0] = (double)e; d[1] = (double)s; d[2] = (double)cfro;
    __threadfence();                       // release: stores visible device-wide
    rank = atomicAdd(ticket, 1u) + 1u;
  }
  rank = __shfl(rank, 0);
  if (rank == (unsigned)NBLK2) {           // last block: whole wave reduces
    __threadfence();                       // acquire
    double ee = 0.0, ss = 0.0, cc = 0.0;
#pragma unroll
    for (int g = 0; g < NBLK2 / 64; ++g) {
      double* d = bsum + 3 * (size_t)(threadIdx.x + 64 * g);
      ee += __hip_atomic_load(&d[0], __ATOMIC_RELAXED, __HIP_MEMORY_SCOPE_AGENT);
      ss += __hip_atomic_load(&d[1], __ATOMIC_RELAXED, __HIP_MEMORY_SCOPE_AGENT);
      cc += __hip_atomic_load(&d[2], __ATOMIC_RELAXED, __HIP_MEMORY_SCOPE_AGENT);
    }
#pragma unroll
    for (int off = 32; off > 0; off >>= 1) {
      ee += __shfl_down(ee, off);
      ss += __shfl_down(ss, off);
      cc += __shfl_down(cc, off);
    }
    if (threadIdx.x == 0) {
      const double BN = (double)BATCH * (double)NPTS;
      out[0] = (float)(ee / BN + 0.5 * (1.0 - ss / (BN * (double)KNN)) + 0.5 * (cc / BN));
    }
  }
}

extern "C" void kernel_launch(void* const* d_in, const int* in_sizes, int n_in,
                              void* d_out, int out_size, void* d_ws, size_t ws_size,
                              hipStream_t stream) {
  const float* pred = (const float*)d_in[0];
  const float* tgt  = (const float*)d_in[1];
  uint32_t* ticket  = (uint32_t*)((char*)d_ws + 64);           // 1 u32
  double*   bsum    = (double*)((char*)d_ws + 4096);           // 256 x 3 doubles
  uint32_t* partial = (uint32_t*)((char*)d_ws + 65536);        // 8.4 MB
  float*    pside   = (float*)((char*)d_ws + (16u << 20));     // 8 MB packed sidecar

  knn_partial_k<<<2 * BATCH * (NPTS / 256) * NC, 256, 0, stream>>>(
      pred, tgt, partial, pside, ticket);
  loss_k<<<NBLK2, 64, 0, stream>>>(
      pred, tgt, partial, bsum, ticket, (float*)d_out);
}

// Round 4
// 96.478 us; speedup vs baseline: 1.0486x; 1.0486x over previous
//
#include <hip/hip_runtime.h>
#include <cstdint>
#include <cstddef>

#define NPTS   4096
#define BATCH  4
#define KNN    8
#define NC     16          // chunks per cloud scan
#define CHN    (NPTS / NC) // 256 candidates per chunk
#define PD     4           // partial STORAGE depth per chunk (uint4; slot 3 = pad)
#define SD     3           // scan list depth (top-3/chunk)
#define EPS_F  1e-12f
#define NBLK2  ((BATCH * NPTS) / 64)   // 256 loss blocks

__device__ __forceinline__ uint32_t u32min(uint32_t a, uint32_t b) { return a < b ? a : b; }
__device__ __forceinline__ uint32_t u32max(uint32_t a, uint32_t b) { return a > b ? a : b; }

// v_med3_u32: for sorted a<=b, med3(a,b,x) == clamp(x,a,b) — one instruction.
__device__ __forceinline__ uint32_t umed3(uint32_t a, uint32_t b, uint32_t c) {
  uint32_t d;
  asm("v_med3_u32 %0, %1, %2, %3" : "=v"(d) : "v"(a), "v"(b), "v"(c));
  return d;
}

// Insert key into ascending D-list, dropping the largest: 1 min + (D-1) med3.
template <int D>
__device__ __forceinline__ void insertD(uint32_t (&loc)[D], uint32_t key) {
  uint32_t prev = loc[0];
  loc[0] = u32min(prev, key);
#pragma unroll
  for (int m = 1; m < D; ++m) {
    const uint32_t cur = loc[m];
    loc[m] = umed3(prev, cur, key);
    prev = cur;
  }
}

// Two sorted-4 lists -> one fully sorted 8 (bitonic cleanup, 12 CEs).
__device__ __forceinline__ void merge44(const uint2 a0, const uint2 a1,
                                        const uint2 b0, const uint2 b1,
                                        uint32_t s[KNN]) {
  s[0] = a0.x; s[1] = a0.y; s[2] = a1.x; s[3] = a1.y;
  s[4] = b1.y; s[5] = b1.x; s[6] = b0.y; s[7] = b0.x;  // b reversed -> bitonic
#define CEU(x, y) { uint32_t lo = u32min(s[x], s[y]); uint32_t hi = u32max(s[x], s[y]); s[x] = lo; s[y] = hi; }
  CEU(0,4) CEU(1,5) CEU(2,6) CEU(3,7)
  CEU(0,2) CEU(1,3) CEU(4,6) CEU(5,7)
  CEU(0,1) CEU(2,3) CEU(4,5) CEU(6,7)
#undef CEU
}

// Dual-list candidate scan: even-j candidates insert into E, odd-j into O.
// The two insert chains are data-independent -> 2x ILP on the serial
// loc-dependency that bounds the single-list version. Union's top-D at
// chunk end (merge44) is bit-identical to the single-list top-D.
// Arithmetic per candidate unchanged from the proven R1 kernel.
template <int D>
__device__ __forceinline__ void scan_chunk_dual(const float4* __restrict__ c4, int j0,
                                                float xix, float xiy, float xiz,
                                                uint32_t (&E)[D], uint32_t (&O)[D]) {
#pragma unroll
  for (int k = 0; k < D; ++k) { E[k] = 0xFFFFFFFFu; O[k] = 0xFFFFFFFFu; }
#pragma unroll 2
  for (int t4 = 0; t4 < CHN / 4; ++t4) {
    const float4 q0 = c4[3 * t4 + 0];  // x0 y0 z0 x1
    const float4 q1 = c4[3 * t4 + 1];  // y1 z1 x2 y2
    const float4 q2 = c4[3 * t4 + 2];  // z2 x3 y3 z3
    const uint32_t jb = (uint32_t)(j0 + 4 * t4);
    {
      const float dx = xix - q0.x, dy = xiy - q0.y, dz = xiz - q0.z;
      const float d2 = fmaf(dx, dx, fmaf(dy, dy, dz * dz));
      insertD<D>(E, (__float_as_uint(d2) & 0xFFFFF000u) | (jb + 0u));
    }
    {
      const float dx = xix - q0.w, dy = xiy - q1.x, dz = xiz - q1.y;
      const float d2 = fmaf(dx, dx, fmaf(dy, dy, dz * dz));
      insertD<D>(O, (__float_as_uint(d2) & 0xFFFFF000u) | (jb + 1u));
    }
    {
      const float dx = xix - q1.z, dy = xiy - q1.w, dz = xiz - q2.x;
      const float d2 = fmaf(dx, dx, fmaf(dy, dy, dz * dz));
      insertD<D>(E, (__float_as_uint(d2) & 0xFFFFF000u) | (jb + 2u));
    }
    {
      const float dx = xix - q2.y, dy = xiy - q2.z, dz = xiz - q2.w;
      const float d2 = fmaf(dx, dx, fmaf(dy, dy, dz * dz));
      insertD<D>(O, (__float_as_uint(d2) & 0xFFFFF000u) | (jb + 3u));
    }
  }
}

// ---------------------------------------------------------------------------
// Kernel 1: per-(cloud,batch,point,chunk) top-3 by truncated key (top-4 with
// rank-0 self-drop for the self chunk — block-uniform branch). Key =
// (float_bits(d2) & 0xFFFFF000) | j; ties -> ascending j (lax.top_k).
// Structure = R1 (proven, bit-exact): LDS-staged chunk, uniform ds_read_b128
// broadcasts, compiler-counted lgkmcnt pipelining. Change: dual even/odd
// insert lists merged exactly at chunk end (ILP experiment — the single-list
// serial loc-chain is the suspected issue-efficiency limiter).
// ---------------------------------------------------------------------------
__global__ void __launch_bounds__(256, 8)
knn_partial_k(const float* __restrict__ pred, const float* __restrict__ tgt,
              uint32_t* __restrict__ partial, uint32_t* __restrict__ ticket) {
  if (blockIdx.x == 0 && threadIdx.x == 0) *ticket = 0u;

  __shared__ float4 lds4[3 * CHN / 4];   // 192 x float4 = 3 KB chunk stream

  int bx = blockIdx.x;
  const int chunk = bx & (NC - 1); bx /= NC;
  const int ig    = bx & 15; bx >>= 4;
  const int b     = bx & 3;  bx >>= 2;
  const int cloud = bx;  // 0 = pred, 1 = target

  const float* __restrict__ pts = (cloud ? tgt : pred) + (size_t)b * NPTS * 3;
  const int tid = threadIdx.x;
  const int i = ig * 256 + tid;
  const int j0 = chunk * CHN;

  // Stage this chunk's raw xyz stream into LDS (coalesced, 1 float4/thread).
  const float4* __restrict__ g4 = (const float4*)(pts + 3 * j0);
  if (tid < 3 * CHN / 4) lds4[tid] = g4[tid];

  const float xix = pts[3 * i + 0];
  const float xiy = pts[3 * i + 1];
  const float xiz = pts[3 * i + 2];
  __syncthreads();

  const float4* c4 = lds4;
  uint4 o;
  if (ig == chunk) {           // self chunk: dual depth-4, exact merge, drop rank 0
    uint32_t E[SD + 1], O[SD + 1];
    scan_chunk_dual<SD + 1>(c4, j0, xix, xiy, xiz, E, O);
    uint32_t s[KNN];
    merge44(make_uint2(E[0], E[1]), make_uint2(E[2], E[3]),
            make_uint2(O[0], O[1]), make_uint2(O[2], O[3]), s);
    o = make_uint4(s[1], s[2], s[3], 0xFFFFFFFFu);
  } else {                     // dual depth-3, pad to 4, exact merge
    uint32_t E[SD], O[SD];
    scan_chunk_dual<SD>(c4, j0, xix, xiy, xiz, E, O);
    uint32_t s[KNN];
    merge44(make_uint2(E[0], E[1]), make_uint2(E[2], 0xFFFFFFFFu),
            make_uint2(O[0], O[1]), make_uint2(O[2], 0xFFFFFFFFu), s);
    o = make_uint4(s[0], s[1], s[2], 0xFFFFFFFFu);
  }
  uint32_t* p = partial +
      ((((size_t)(cloud * BATCH + b) * NC + chunk) * NPTS) + (size_t)i) * PD;
  *(uint4*)p = o;
}

// Merge two sorted-ascending 8-lists, keep the smallest 8, sorted.
__device__ __forceinline__ void merge2(uint32_t A[KNN], const uint32_t B[KNN]) {
  uint32_t t[KNN];
#pragma unroll
  for (int m = 0; m < KNN; ++m) t[m] = u32min(A[m], B[KNN - 1 - m]);
#define CEU(x, y) { uint32_t lo = u32min(t[x], t[y]); uint32_t hi = u32max(t[x], t[y]); t[x] = lo; t[y] = hi; }
  CEU(0,4) CEU(1,5) CEU(2,6) CEU(3,7)
  CEU(0,2) CEU(1,3) CEU(4,6) CEU(5,7)
  CEU(0,1) CEU(2,3) CEU(4,5) CEU(6,7)
#undef CEU
#pragma unroll
  for (int m = 0; m < KNN; ++m) A[m] = t[m];
}

// Merge all NC=16 sorted-4 lists for point i -> global top-8 (sorted).
__device__ __forceinline__ void merge_all(const uint32_t* __restrict__ base,
                                          int i, uint32_t v[KNN]) {
  const size_t stride = (size_t)NPTS * PD;
  const uint32_t* p = base + (size_t)i * PD;
  uint2 q[NC][2];
#pragma unroll
  for (int c = 0; c < NC; ++c) {
    q[c][0] = *(const uint2*)(p + (size_t)c * stride);
    q[c][1] = *(const uint2*)(p + (size_t)c * stride + 2);
  }
  uint32_t L[NC / 2][KNN];
#pragma unroll
  for (int c = 0; c < NC / 2; ++c)
    merge44(q[2 * c][0], q[2 * c][1], q[2 * c + 1][0], q[2 * c + 1][1], L[c]);
  merge2(L[0], L[1]); merge2(L[2], L[3]); merge2(L[4], L[5]); merge2(L[6], L[7]);
  merge2(L[0], L[2]); merge2(L[4], L[6]);
  merge2(L[0], L[4]);
#pragma unroll
  for (int m = 0; m < KNN; ++m) v[m] = L[0][m];
}

// Per-cloud: coord gather (8 independent loads), density/cov/unit vectors.
__device__ __forceinline__ void cloud_stats(const float* __restrict__ C, int i,
                                            const uint32_t v[KNN],
                                            float& dsum, float cov[6],
                                            float nx[KNN], float ny[KNN], float nz[KNN]) {
  const float qx = C[3 * i], qy = C[3 * i + 1], qz = C[3 * i + 2];
  float jx[KNN], jy[KNN], jz[KNN];
#pragma unroll
  for (int k = 0; k < KNN; ++k) {
    const int j = (int)(v[k] & 0xFFFu);
    jx[k] = C[3 * j]; jy[k] = C[3 * j + 1]; jz[k] = C[3 * j + 2];
  }
  dsum = 0.f;
#pragma unroll
  for (int m = 0; m < 6; ++m) cov[m] = 0.f;
#pragma unroll
  for (int k = 0; k < KNN; ++k) {
    const float ax = jx[k] - qx, ay = jy[k] - qy, az = jz[k] - qz;
    const float d2 = fmaf(ax, ax, fmaf(ay, ay, az * az));
    const float dist = sqrtf(fmaxf(d2, EPS_F));
    const float inv = 1.0f / fmaxf(dist, EPS_F);
    dsum += dist;
    cov[0] += ax * ax; cov[1] += ay * ay; cov[2] += az * az;
    cov[3] += ax * ay; cov[4] += ax * az; cov[5] += ay * az;
    nx[k] = ax * inv; ny[k] = ay * inv; nz[k] = az * inv;
  }
}

// ---------------------------------------------------------------------------
// Kernel 2 — R1/R2 verbatim (proven): plain per-block stores + ticket finalize.
// ---------------------------------------------------------------------------
__global__ void __launch_bounds__(64, 1)
loss_k(const float* __restrict__ pred, const float* __restrict__ tgt,
       const uint32_t* __restrict__ partial, double* __restrict__ bsum,
       uint32_t* __restrict__ ticket, float* __restrict__ out) {
  const int p = blockIdx.x * 64 + threadIdx.x;   // 0 .. 16383
  const int b = p >> 12;
  const int i = p & (NPTS - 1);

  const float* __restrict__ P = pred + (size_t)b * NPTS * 3;
  const float* __restrict__ T = tgt  + (size_t)b * NPTS * 3;

  const size_t cstride = (size_t)NC * NPTS * PD;
  uint32_t vp[KNN], vt[KNN];
  merge_all(partial + (size_t)(0 * BATCH + b) * cstride, i, vp);
  merge_all(partial + (size_t)(1 * BATCH + b) * cstride, i, vt);

  float dsp, dst, pcov[6], tcov[6];
  float pnx[KNN], pny[KNN], pnz[KNN], tnx[KNN], tny[KNN], tnz[KNN];
  cloud_stats(P, i, vp, dsp, pcov, pnx, pny, pnz);
  cloud_stats(T, i, vt, dst, tcov, tnx, tny, tnz);

  float sdot = 0.f;
#pragma unroll
  for (int k = 0; k < KNN; ++k)
    sdot += pnx[k] * tnx[k] + pny[k] * tny[k] + pnz[k] * tnz[k];

  const float densp = dsp * (1.0f / KNN);
  const float denst = dst * (1.0f / KNN);
  float e = (densp - denst) * (densp - denst);

  const float dxx = (pcov[0] - tcov[0]) * (1.0f / KNN);
  const float dyy = (pcov[1] - tcov[1]) * (1.0f / KNN);
  const float dzz = (pcov[2] - tcov[2]) * (1.0f / KNN);
  const float dxy = (pcov[3] - tcov[3]) * (1.0f / KNN);
  const float dxz = (pcov[4] - tcov[4]) * (1.0f / KNN);
  const float dyz = (pcov[5] - tcov[5]) * (1.0f / KNN);
  float cfro = sqrtf(dxx * dxx + dyy * dyy + dzz * dzz
                     + 2.0f * (dxy * dxy + dxz * dxz + dyz * dyz));
  float s = sdot;

#pragma unroll
  for (int off = 32; off > 0; off >>= 1) {
    e    += __shfl_down(e, off);
    s    += __shfl_down(s, off);
    cfro += __shfl_down(cfro, off);
  }

  unsigned rank = 0u;
  if (threadIdx.x == 0) {
    double* d = bsum + 3 * (size_t)blockIdx.x;
    d[0] = (double)e; d[1] = (double)s; d[2] = (double)cfro;
    __threadfence();                       // release: stores visible device-wide
    rank = atomicAdd(ticket, 1u) + 1u;
  }
  rank = __shfl(rank, 0);
  if (rank == (unsigned)NBLK2) {           // last block: whole wave reduces
    __threadfence();                       // acquire
    double ee = 0.0, ss = 0.0, cc = 0.0;
#pragma unroll
    for (int g = 0; g < NBLK2 / 64; ++g) {
      double* d = bsum + 3 * (size_t)(threadIdx.x + 64 * g);
      ee += __hip_atomic_load(&d[0], __ATOMIC_RELAXED, __HIP_MEMORY_SCOPE_AGENT);
      ss += __hip_atomic_load(&d[1], __ATOMIC_RELAXED, __HIP_MEMORY_SCOPE_AGENT);
      cc += __hip_atomic_load(&d[2], __ATOMIC_RELAXED, __HIP_MEMORY_SCOPE_AGENT);
    }
#pragma unroll
    for (int off = 32; off > 0; off >>= 1) {
      ee += __shfl_down(ee, off);
      ss += __shfl_down(ss, off);
      cc += __shfl_down(cc, off);
    }
    if (threadIdx.x == 0) {
      const double BN = (double)BATCH * (double)NPTS;
      out[0] = (float)(ee / BN + 0.5 * (1.0 - ss / (BN * (double)KNN)) + 0.5 * (cc / BN));
    }
  }
}

extern "C" void kernel_launch(void* const* d_in, const int* in_sizes, int n_in,
                              void* d_out, int out_size, void* d_ws, size_t ws_size,
                              hipStream_t stream) {
  const float* pred = (const float*)d_in[0];
  const float* tgt  = (const float*)d_in[1];
  uint32_t* ticket  = (uint32_t*)((char*)d_ws + 64);     // 1 u32
  double*   bsum    = (double*)((char*)d_ws + 4096);     // 256 x 3 doubles (6 KB)
  uint32_t* partial = (uint32_t*)((char*)d_ws + 65536);  // 8.4 MB

  knn_partial_k<<<2 * BATCH * (NPTS / 256) * NC, 256, 0, stream>>>(
      pred, tgt, partial, ticket);
  loss_k<<<NBLK2, 64, 0, stream>>>(
      pred, tgt, partial, bsum, ticket, (float*)d_out);
}